// Round 1
// baseline (682.533 us; speedup 1.0000x reference)
//
#include <hip/hip_runtime.h>

#define D 512
#define NS 4096
#define NROWS 8192
#define BM 128
#define BK 32
#define TILES 32              // 4096/128
#define TILES_PER_TYPE 1024   // 32*32
#define NBLK_GEMM 3072        // 3 types

// ---------------- k1: per-row L2 norm -> inv, sq ----------------
__global__ __launch_bounds__(256) void k_rownorm(const float* __restrict__ src,
                                                 const float* __restrict__ tgt,
                                                 float* __restrict__ inv,
                                                 float* __restrict__ sq) {
  int r = blockIdx.x;
  const float* p = (r < NS) ? (src + (size_t)r * D) : (tgt + (size_t)(r - NS) * D);
  int t = threadIdx.x;
  float x0 = p[t];
  float x1 = p[t + 256];
  float s = x0 * x0 + x1 * x1;
  #pragma unroll
  for (int off = 32; off; off >>= 1) s += __shfl_down(s, off);
  __shared__ float ls[4];
  if ((t & 63) == 0) ls[t >> 6] = s;
  __syncthreads();
  if (t == 0) {
    float tot = ls[0] + ls[1] + ls[2] + ls[3];
    float nrm = sqrtf(tot);
    float iv = 1.0f / fmaxf(nrm, 1e-12f);
    inv[r] = iv;
    sq[r] = tot * iv * iv;
  }
}

// ---------------- k2: partial column sums of normalized rows ----------------
__global__ __launch_bounds__(512) void k_colsum(const float* __restrict__ src,
                                                const float* __restrict__ tgt,
                                                const float* __restrict__ inv,
                                                float* __restrict__ Spart) {
  int b = blockIdx.x;      // 32 blocks
  int t = threadIdx.x;     // 512 threads = one column each
  int r0 = b * 256;
  float a = 0.f;
  for (int r = r0; r < r0 + 256; ++r) {
    const float* p = (r < NS) ? (src + (size_t)r * D) : (tgt + (size_t)(r - NS) * D);
    a += p[t] * inv[r];
  }
  Spart[(size_t)b * D + t] = a;
}

// ---------------- k3: bandwidth via closed form -> exp2 coefficients ----------------
__global__ __launch_bounds__(256) void k_prep(const float* __restrict__ sq,
                                              const float* __restrict__ Spart,
                                              float* __restrict__ na) {
  int t = threadIdx.x;
  double ssq = 0.0;
  for (int i = t; i < NROWS; i += 256) ssq += (double)sq[i];
  double ss2 = 0.0;
  for (int c = t; c < D; c += 256) {
    double s = 0.0;
    for (int b = 0; b < 32; ++b) s += (double)Spart[(size_t)b * D + c];
    ss2 += s * s;
  }
  #pragma unroll
  for (int off = 32; off; off >>= 1) {
    ssq += __shfl_down(ssq, off);
    ss2 += __shfl_down(ss2, off);
  }
  __shared__ double l1[4], l2[4];
  if ((t & 63) == 0) { l1[t >> 6] = ssq; l2[t >> 6] = ss2; }
  __syncthreads();
  if (t == 0) {
    double SSQ = l1[0] + l1[1] + l1[2] + l1[3];
    double SS2 = l2[0] + l2[1] + l2[2] + l2[3];
    double n = (double)NROWS;
    double sum_d2 = 2.0 * n * SSQ - 2.0 * SS2;
    double bw = sum_d2 / (n * n - n) + 1e-8;     // + EPS
    bw = bw * 0.25;                               // / KERNEL_MUL^(KERNEL_NUM//2)
    const double LOG2E = 1.4426950408889634;
    #pragma unroll
    for (int m = 0; m < 5; ++m) na[m] = (float)(-LOG2E / (bw * (double)(1 << m)));
  }
}

// ---------------- k4: fused block-GEMM + kernel-sum epilogue ----------------
__global__ __launch_bounds__(256) void k_gemm(const float* __restrict__ src,
                                              const float* __restrict__ tgt,
                                              const float* __restrict__ inv,
                                              const float* __restrict__ sq,
                                              const float* __restrict__ na,
                                              double* __restrict__ part) {
  __shared__ float As[BK][BM + 4];
  __shared__ float Bs[BK][BM + 4];
  __shared__ double red[4];

  int bid = blockIdx.x;
  int type = bid >> 10;          // 0: XX, 1: YY, 2: XY
  int rem = bid & 1023;
  int bi = rem >> 5;
  int bj = rem & 31;

  const float* Ap = (type == 1) ? tgt : src;
  const float* Bp = (type == 0) ? src : tgt;
  int offA = (type == 1) ? NS : 0;
  int offB = (type == 0) ? 0 : NS;

  int t = threadIdx.x;
  int tr = t >> 1;               // 0..127: staging row within tile
  int tc = (t & 1) * 16;         // 0 or 16: staging k-base

  int rA = bi * BM + tr;
  int rB = bj * BM + tr;
  float ivA = inv[offA + rA];
  float ivB = inv[offB + rB];
  const float* gA = Ap + (size_t)rA * D + tc;
  const float* gB = Bp + (size_t)rB * D + tc;

  int r0 = (t >> 4) * 8;
  int c0 = (t & 15) * 8;

  float acc[8][8];
  #pragma unroll
  for (int i = 0; i < 8; ++i)
    #pragma unroll
    for (int j = 0; j < 8; ++j) acc[i][j] = 0.f;

  for (int kt = 0; kt < D / BK; ++kt) {
    float4 av[4], bv[4];
    const float4* ga4 = (const float4*)(gA + kt * BK);
    const float4* gb4 = (const float4*)(gB + kt * BK);
    #pragma unroll
    for (int j = 0; j < 4; ++j) { av[j] = ga4[j]; bv[j] = gb4[j]; }
    __syncthreads();
    #pragma unroll
    for (int j = 0; j < 4; ++j) {
      As[tc + 4 * j + 0][tr] = av[j].x * ivA;
      As[tc + 4 * j + 1][tr] = av[j].y * ivA;
      As[tc + 4 * j + 2][tr] = av[j].z * ivA;
      As[tc + 4 * j + 3][tr] = av[j].w * ivA;
      Bs[tc + 4 * j + 0][tr] = bv[j].x * ivB;
      Bs[tc + 4 * j + 1][tr] = bv[j].y * ivB;
      Bs[tc + 4 * j + 2][tr] = bv[j].z * ivB;
      Bs[tc + 4 * j + 3][tr] = bv[j].w * ivB;
    }
    __syncthreads();
    #pragma unroll
    for (int k = 0; k < BK; ++k) {
      float a[8], b[8];
      *(float4*)&a[0] = *(const float4*)&As[k][r0];
      *(float4*)&a[4] = *(const float4*)&As[k][r0 + 4];
      *(float4*)&b[0] = *(const float4*)&Bs[k][c0];
      *(float4*)&b[4] = *(const float4*)&Bs[k][c0 + 4];
      #pragma unroll
      for (int i = 0; i < 8; ++i)
        #pragma unroll
        for (int j = 0; j < 8; ++j)
          acc[i][j] = fmaf(a[i], b[j], acc[i][j]);
    }
  }

  // epilogue: d2 -> 5-kernel exp2 sum, fp64 accumulate
  float nam[5];
  #pragma unroll
  for (int m = 0; m < 5; ++m) nam[m] = na[m];
  int gi = offA + bi * BM + r0;
  int gj = offB + bj * BM + c0;
  float sqa[8], sqb[8];
  #pragma unroll
  for (int i = 0; i < 8; ++i) { sqa[i] = sq[gi + i]; sqb[i] = sq[gj + i]; }
  double local = 0.0;
  #pragma unroll
  for (int i = 0; i < 8; ++i) {
    #pragma unroll
    for (int j = 0; j < 8; ++j) {
      float d2 = fmaf(-2.f, acc[i][j], sqa[i] + sqb[j]);
      d2 = fmaxf(d2, 0.f);
      float kv = 0.f;
      #pragma unroll
      for (int m = 0; m < 5; ++m) kv += __builtin_amdgcn_exp2f(d2 * nam[m]);
      local += (double)kv;
    }
  }
  #pragma unroll
  for (int off = 32; off; off >>= 1) local += __shfl_down(local, off);
  if ((t & 63) == 0) red[t >> 6] = local;
  __syncthreads();
  if (t == 0) part[bid] = red[0] + red[1] + red[2] + red[3];
}

// ---------------- k5: final fp64 reduction + loss ----------------
__global__ __launch_bounds__(256) void k_final(const double* __restrict__ part,
                                               float* __restrict__ out) {
  int t = threadIdx.x;
  double a0 = 0.0, a1 = 0.0, a2 = 0.0;
  for (int i = t; i < TILES_PER_TYPE; i += 256) {
    a0 += part[i];
    a1 += part[TILES_PER_TYPE + i];
    a2 += part[2 * TILES_PER_TYPE + i];
  }
  #pragma unroll
  for (int off = 32; off; off >>= 1) {
    a0 += __shfl_down(a0, off);
    a1 += __shfl_down(a1, off);
    a2 += __shfl_down(a2, off);
  }
  __shared__ double r0[4], r1[4], r2[4];
  if ((t & 63) == 0) { r0[t >> 6] = a0; r1[t >> 6] = a1; r2[t >> 6] = a2; }
  __syncthreads();
  if (t == 0) {
    double A0 = r0[0] + r0[1] + r0[2] + r0[3];
    double A1 = r1[0] + r1[1] + r1[2] + r1[3];
    double A2 = r2[0] + r2[1] + r2[2] + r2[3];
    double ns = (double)NS;
    double loss = (A0 - 5.0 * ns) / (ns * (ns - 1.0))
                + (A1 - 5.0 * ns) / (ns * (ns - 1.0))
                - 2.0 * A2 / (ns * ns);
    out[0] = (float)loss;
  }
}

extern "C" void kernel_launch(void* const* d_in, const int* in_sizes, int n_in,
                              void* d_out, int out_size, void* d_ws, size_t ws_size,
                              hipStream_t stream) {
  (void)in_sizes; (void)n_in; (void)out_size; (void)ws_size;
  const float* src = (const float*)d_in[0];
  const float* tgt = (const float*)d_in[1];
  float* out = (float*)d_out;
  char* ws = (char*)d_ws;

  // ws layout (bytes):
  double* part  = (double*)ws;                       // 3072 * 8  = 24576
  float*  inv   = (float*)(ws + 24576);              // 8192 * 4  = 32768 -> 57344
  float*  sq    = (float*)(ws + 57344);              // 8192 * 4  = 32768 -> 90112
  float*  Spart = (float*)(ws + 90112);              // 32*512*4  = 65536 -> 155648
  float*  na    = (float*)(ws + 155648);             // 5 * 4

  hipLaunchKernelGGL(k_rownorm, dim3(NROWS), dim3(256), 0, stream, src, tgt, inv, sq);
  hipLaunchKernelGGL(k_colsum, dim3(32), dim3(512), 0, stream, src, tgt, inv, Spart);
  hipLaunchKernelGGL(k_prep, dim3(1), dim3(256), 0, stream, sq, Spart, na);
  hipLaunchKernelGGL(k_gemm, dim3(NBLK_GEMM), dim3(256), 0, stream, src, tgt, inv, sq, na, part);
  hipLaunchKernelGGL(k_final, dim3(1), dim3(256), 0, stream, part, out);
}

// Round 2
// 230.862 us; speedup vs baseline: 2.9565x; 2.9565x over previous
//
#include <hip/hip_runtime.h>

#define D 512
#define NS 4096
#define NROWS 8192
#define TILES 32
#define T_SYM 528                         // 32*33/2 triangular tiles
#define NBLK_GEMM (2 * T_SYM + TILES * TILES)   // 528+528+1024 = 2080

typedef __attribute__((ext_vector_type(8))) short bf16x8;
typedef __attribute__((ext_vector_type(4))) float f32x4;

__device__ __forceinline__ unsigned short f2bf(float f) {
  unsigned int u = __float_as_uint(f);
  u += 0x7fffu + ((u >> 16) & 1u);        // RNE
  return (unsigned short)(u >> 16);
}
__device__ __forceinline__ float bf2f(unsigned short h) {
  return __uint_as_float(((unsigned int)h) << 16);
}
__device__ __forceinline__ void gload_lds16(const void* g, void* l) {
  __builtin_amdgcn_global_load_lds(
      (const __attribute__((address_space(1))) unsigned int*)g,
      (__attribute__((address_space(3))) unsigned int*)l, 16, 0, 0);
}

// ---------------- k1: per-row L2 norm -> inv, sq, and bf16 hi/lo split ----------------
// 1 wave per row, 4 rows per block.
__global__ __launch_bounds__(256) void k_rownorm(const float* __restrict__ src,
                                                 const float* __restrict__ tgt,
                                                 float* __restrict__ inv,
                                                 float* __restrict__ sq,
                                                 unsigned short* __restrict__ hi,
                                                 unsigned short* __restrict__ lo) {
  int w = threadIdx.x >> 6, l = threadIdx.x & 63;
  int r = blockIdx.x * 4 + w;
  const float* p = (r < NS) ? (src + (size_t)r * D) : (tgt + (size_t)(r - NS) * D);
  float4 v0 = *(const float4*)(p + l * 8);
  float4 v1 = *(const float4*)(p + l * 8 + 4);
  float x[8] = {v0.x, v0.y, v0.z, v0.w, v1.x, v1.y, v1.z, v1.w};
  float s = 0.f;
  #pragma unroll
  for (int j = 0; j < 8; ++j) s += x[j] * x[j];
  #pragma unroll
  for (int off = 1; off < 64; off <<= 1) s += __shfl_xor(s, off);
  float iv = 1.0f / fmaxf(sqrtf(s), 1e-12f);
  if (l == 0) { inv[r] = iv; sq[r] = s * iv * iv; }
  unsigned short hs[8], ls[8];
  #pragma unroll
  for (int j = 0; j < 8; ++j) {
    float xn = x[j] * iv;
    unsigned short h = f2bf(xn);
    hs[j] = h;
    ls[j] = f2bf(xn - bf2f(h));
  }
  *(uint4*)&hi[(size_t)r * D + l * 8] = *(uint4*)hs;
  *(uint4*)&lo[(size_t)r * D + l * 8] = *(uint4*)ls;
}

// ---------------- k2: partial column sums of normalized rows ----------------
__global__ __launch_bounds__(512) void k_colsum(const float* __restrict__ src,
                                                const float* __restrict__ tgt,
                                                const float* __restrict__ inv,
                                                float* __restrict__ Spart) {
  int b = blockIdx.x;      // 256 blocks x 32 rows
  int t = threadIdx.x;     // 512 threads = one column each
  int r0 = b * 32;
  float a = 0.f;
  for (int r = r0; r < r0 + 32; ++r) {
    const float* p = (r < NS) ? (src + (size_t)r * D) : (tgt + (size_t)(r - NS) * D);
    a += p[t] * inv[r];
  }
  Spart[(size_t)b * D + t] = a;
}

// ---------------- k3: bandwidth via closed form -> exp2 coefficients ----------------
__global__ __launch_bounds__(256) void k_prep(const float* __restrict__ sq,
                                              const float* __restrict__ Spart,
                                              float* __restrict__ na) {
  int t = threadIdx.x;
  double ssq = 0.0;
  for (int i = t; i < NROWS; i += 256) ssq += (double)sq[i];
  double ss2 = 0.0;
  for (int c = t; c < D; c += 256) {
    double s = 0.0;
    for (int b = 0; b < 256; ++b) s += (double)Spart[(size_t)b * D + c];
    ss2 += s * s;
  }
  #pragma unroll
  for (int off = 32; off; off >>= 1) {
    ssq += __shfl_down(ssq, off);
    ss2 += __shfl_down(ss2, off);
  }
  __shared__ double l1[4], l2[4];
  if ((t & 63) == 0) { l1[t >> 6] = ssq; l2[t >> 6] = ss2; }
  __syncthreads();
  if (t == 0) {
    double SSQ = l1[0] + l1[1] + l1[2] + l1[3];
    double SS2 = l2[0] + l2[1] + l2[2] + l2[3];
    double n = (double)NROWS;
    double sum_d2 = 2.0 * n * SSQ - 2.0 * SS2;
    double bw = sum_d2 / (n * n - n) + 1e-8;     // + EPS
    bw = bw * 0.25;                               // / KERNEL_MUL^(KERNEL_NUM//2)
    const double LOG2E = 1.4426950408889634;
    #pragma unroll
    for (int m = 0; m < 5; ++m) na[m] = (float)(-LOG2E / (bw * (double)(1 << m)));
  }
}

// ---------------- k4: bf16x3-split MFMA GEMM + fused kernel-sum epilogue ----------------
// 128x128 tile, BK=32, 4 waves (2x2), each wave 64x64 via 4x4 16x16x32 frags.
// Upper-triangle-only for XX/YY (off-diag tiles weighted 2x).
__global__ __launch_bounds__(256) void k_gemm(const unsigned short* __restrict__ hi,
                                              const unsigned short* __restrict__ lo,
                                              const float* __restrict__ sq,
                                              const float* __restrict__ na,
                                              double* __restrict__ part) {
  __shared__ unsigned short lds[16384];   // Ahi 0 | Alo 4096 | Bhi 8192 | Blo 12288 (elements)
  __shared__ double red[4];

  int bid = blockIdx.x;
  int type, bi, bj;
  float wgt = 1.f;
  if (bid < 2 * T_SYM) {
    type = (bid >= T_SYM);
    int idx = bid - type * T_SYM;
    bi = 0;
    while (idx >= TILES - bi) { idx -= TILES - bi; ++bi; }
    bj = bi + idx;
    wgt = (bi == bj) ? 1.f : 2.f;
  } else {
    type = 2;
    int rem = bid - 2 * T_SYM;
    bi = rem >> 5;
    bj = rem & 31;
  }
  int offA = (type == 1) ? NS : 0;
  int offB = (type == 0) ? 0 : NS;

  int t = threadIdx.x;
  int w = t >> 6, l = t & 63;
  int wr = w >> 1, wc = w & 1;
  int fr = l & 15, fk = l >> 4;

  // staging: wave w owns one 8KB chunk: 0=Ahi 1=Alo 2=Bhi 3=Blo
  const unsigned short* sarr = (w & 1) ? lo : hi;
  int rbase = ((w < 2) ? (offA + bi * 128) : (offB + bj * 128)) + (l >> 2);
  const unsigned short* gbase = sarr + (size_t)rbase * D + (l & 3) * 8;

  int aoff = (wr * 64 + fr) * 32 + fk * 8;          // + m*512
  int boff = 8192 + (wc * 64 + fr) * 32 + fk * 8;   // + n*512

  f32x4 acc[4][4];
  f32x4 zero = {0.f, 0.f, 0.f, 0.f};
  #pragma unroll
  for (int m = 0; m < 4; ++m)
    #pragma unroll
    for (int n = 0; n < 4; ++n) acc[m][n] = zero;

  for (int kt = 0; kt < D / 32; ++kt) {
    __syncthreads();   // previous compute done before overwrite
    #pragma unroll
    for (int c = 0; c < 8; ++c)
      gload_lds16(gbase + (size_t)c * 16 * D + kt * 32, &lds[w * 4096 + c * 512]);
    __syncthreads();   // staging visible (compiler drains vmcnt at barrier)

    bf16x8 ah[4], al[4], bh[4], bl[4];
    #pragma unroll
    for (int m = 0; m < 4; ++m) {
      ah[m] = *(const bf16x8*)&lds[aoff + m * 512];
      al[m] = *(const bf16x8*)&lds[4096 + aoff + m * 512];
    }
    #pragma unroll
    for (int n = 0; n < 4; ++n) {
      bh[n] = *(const bf16x8*)&lds[boff + n * 512];
      bl[n] = *(const bf16x8*)&lds[4096 + boff + n * 512];
    }
    #pragma unroll
    for (int m = 0; m < 4; ++m)
      #pragma unroll
      for (int n = 0; n < 4; ++n) {
        acc[m][n] = __builtin_amdgcn_mfma_f32_16x16x32_bf16(ah[m], bh[n], acc[m][n], 0, 0, 0);
        acc[m][n] = __builtin_amdgcn_mfma_f32_16x16x32_bf16(ah[m], bl[n], acc[m][n], 0, 0, 0);
        acc[m][n] = __builtin_amdgcn_mfma_f32_16x16x32_bf16(al[m], bh[n], acc[m][n], 0, 0, 0);
      }
  }

  // epilogue: D row = fk*4 + j, col = fr  (m89-verified C/D layout)
  float nam[5];
  #pragma unroll
  for (int m2 = 0; m2 < 5; ++m2) nam[m2] = na[m2];
  int gi = offA + bi * 128 + wr * 64;
  int gj = offB + bj * 128 + wc * 64;
  float sqa[4][4], sqb[4];
  #pragma unroll
  for (int m = 0; m < 4; ++m)
    #pragma unroll
    for (int j = 0; j < 4; ++j) sqa[m][j] = sq[gi + m * 16 + fk * 4 + j];
  #pragma unroll
  for (int n = 0; n < 4; ++n) sqb[n] = sq[gj + n * 16 + fr];

  double local = 0.0;
  #pragma unroll
  for (int m = 0; m < 4; ++m)
    #pragma unroll
    for (int n = 0; n < 4; ++n)
      #pragma unroll
      for (int j = 0; j < 4; ++j) {
        float d2 = fmaxf(fmaf(-2.f, acc[m][n][j], sqa[m][j] + sqb[n]), 0.f);
        float kv = 0.f;
        #pragma unroll
        for (int m2 = 0; m2 < 5; ++m2) kv += __builtin_amdgcn_exp2f(d2 * nam[m2]);
        local += (double)kv;
      }
  local *= (double)wgt;
  #pragma unroll
  for (int off = 32; off; off >>= 1) local += __shfl_down(local, off);
  if (l == 0) red[w] = local;
  __syncthreads();
  if (t == 0) part[bid] = red[0] + red[1] + red[2] + red[3];
}

// ---------------- k5: final fp64 reduction + loss ----------------
__global__ __launch_bounds__(256) void k_final(const double* __restrict__ part,
                                               float* __restrict__ out) {
  int t = threadIdx.x;
  double a0 = 0.0, a1 = 0.0, a2 = 0.0;
  for (int i = t; i < T_SYM; i += 256) a0 += part[i];
  for (int i = t; i < T_SYM; i += 256) a1 += part[T_SYM + i];
  for (int i = t; i < TILES * TILES; i += 256) a2 += part[2 * T_SYM + i];
  #pragma unroll
  for (int off = 32; off; off >>= 1) {
    a0 += __shfl_down(a0, off);
    a1 += __shfl_down(a1, off);
    a2 += __shfl_down(a2, off);
  }
  __shared__ double r0[4], r1[4], r2[4];
  if ((t & 63) == 0) { r0[t >> 6] = a0; r1[t >> 6] = a1; r2[t >> 6] = a2; }
  __syncthreads();
  if (t == 0) {
    double A0 = r0[0] + r0[1] + r0[2] + r0[3];
    double A1 = r1[0] + r1[1] + r1[2] + r1[3];
    double A2 = r2[0] + r2[1] + r2[2] + r2[3];
    double ns = (double)NS;
    double loss = (A0 - 5.0 * ns) / (ns * (ns - 1.0))
                + (A1 - 5.0 * ns) / (ns * (ns - 1.0))
                - 2.0 * A2 / (ns * ns);
    out[0] = (float)loss;
  }
}

extern "C" void kernel_launch(void* const* d_in, const int* in_sizes, int n_in,
                              void* d_out, int out_size, void* d_ws, size_t ws_size,
                              hipStream_t stream) {
  (void)in_sizes; (void)n_in; (void)out_size; (void)ws_size;
  const float* src = (const float*)d_in[0];
  const float* tgt = (const float*)d_in[1];
  float* out = (float*)d_out;
  char* ws = (char*)d_ws;

  // ws layout (needs ~17.9 MB):
  double*         part  = (double*)(ws);                  // 2080*8
  float*          inv   = (float*)(ws + 0x10000);         // 32 KB
  float*          sq    = (float*)(ws + 0x18000);         // 32 KB
  float*          Spart = (float*)(ws + 0x20000);         // 512 KB
  float*          na    = (float*)(ws + 0xA0000);         // 20 B
  unsigned short* hi    = (unsigned short*)(ws + 0x100000);   // 8 MB
  unsigned short* lo    = (unsigned short*)(ws + 0x900000);   // 8 MB

  hipLaunchKernelGGL(k_rownorm, dim3(NROWS / 4), dim3(256), 0, stream, src, tgt, inv, sq, hi, lo);
  hipLaunchKernelGGL(k_colsum, dim3(256), dim3(512), 0, stream, src, tgt, inv, Spart);
  hipLaunchKernelGGL(k_prep, dim3(1), dim3(256), 0, stream, sq, Spart, na);
  hipLaunchKernelGGL(k_gemm, dim3(NBLK_GEMM), dim3(256), 0, stream, hi, lo, sq, na, part);
  hipLaunchKernelGGL(k_final, dim3(1), dim3(256), 0, stream, part, out);
}

// Round 3
// 216.393 us; speedup vs baseline: 3.1541x; 1.0669x over previous
//
#include <hip/hip_runtime.h>

#define D 512
#define NS 4096
#define NROWS 8192
#define TILES 32
#define T_SYM 528                               // 32*33/2 triangular tiles
#define NBLK_GEMM (2 * T_SYM + TILES * TILES)   // 528+528+1024 = 2080

typedef __attribute__((ext_vector_type(8))) short bf16x8;
typedef __attribute__((ext_vector_type(4))) float f32x4;

__device__ __forceinline__ unsigned short f2bf(float f) {
  unsigned int u = __float_as_uint(f);
  u += 0x7fffu + ((u >> 16) & 1u);        // RNE
  return (unsigned short)(u >> 16);
}
__device__ __forceinline__ float bf2f(unsigned short h) {
  return __uint_as_float(((unsigned int)h) << 16);
}
__device__ __forceinline__ void gload_lds16(const void* g, void* l) {
  __builtin_amdgcn_global_load_lds(
      (const __attribute__((address_space(1))) unsigned int*)g,
      (__attribute__((address_space(3))) unsigned int*)l, 16, 0, 0);
}

// ---------------- k1: row L2 norm -> sq, bf16 hi/lo split, fused column sums ----------------
// 256 blocks x 32 rows (4 waves x 8 rows). Column sums via LDS + global fp32 atomics
// (bandwidth only needs ~1e-5 relative accuracy, so atomic order is irrelevant).
__global__ __launch_bounds__(256) void k_rownorm(const float* __restrict__ src,
                                                 const float* __restrict__ tgt,
                                                 float* __restrict__ sq,
                                                 unsigned short* __restrict__ hi,
                                                 unsigned short* __restrict__ lo,
                                                 float* __restrict__ colsum) {
  int t = threadIdx.x, w = t >> 6, l = t & 63;
  float csum[8] = {0.f, 0.f, 0.f, 0.f, 0.f, 0.f, 0.f, 0.f};
  for (int i = 0; i < 8; ++i) {
    int r = blockIdx.x * 32 + w * 8 + i;
    const float* p = (r < NS) ? (src + (size_t)r * D) : (tgt + (size_t)(r - NS) * D);
    float4 v0 = *(const float4*)(p + l * 8);
    float4 v1 = *(const float4*)(p + l * 8 + 4);
    float x[8] = {v0.x, v0.y, v0.z, v0.w, v1.x, v1.y, v1.z, v1.w};
    float s = 0.f;
    #pragma unroll
    for (int j = 0; j < 8; ++j) s += x[j] * x[j];
    #pragma unroll
    for (int off = 1; off < 64; off <<= 1) s += __shfl_xor(s, off);
    float iv = 1.0f / fmaxf(sqrtf(s), 1e-12f);
    if (l == 0) sq[r] = s * iv * iv;
    unsigned short hs[8], ls[8];
    #pragma unroll
    for (int j = 0; j < 8; ++j) {
      float xn = x[j] * iv;
      unsigned short h = f2bf(xn);
      hs[j] = h;
      ls[j] = f2bf(xn - bf2f(h));
      csum[j] += xn;
    }
    *(uint4*)&hi[(size_t)r * D + l * 8] = *(uint4*)hs;
    *(uint4*)&lo[(size_t)r * D + l * 8] = *(uint4*)ls;
  }
  __shared__ float cs[4][512];
  #pragma unroll
  for (int j = 0; j < 8; ++j) cs[w][l * 8 + j] = csum[j];
  __syncthreads();
  for (int c = t; c < 512; c += 256)
    atomicAdd(&colsum[c], cs[0][c] + cs[1][c] + cs[2][c] + cs[3][c]);
}

// ---------------- k2: bandwidth via closed form -> single exp2 coefficient ----------------
// sum(d2) = 2n*SSQ - 2*||colsum||^2 ; kernels are powers of u = exp2(d2*na4).
__global__ __launch_bounds__(256) void k_prep(const float* __restrict__ sq,
                                              const float* __restrict__ colsum,
                                              float* __restrict__ na) {
  int t = threadIdx.x;
  double ssq = 0.0;
  for (int i = t; i < NROWS; i += 256) ssq += (double)sq[i];
  double ss2 = 0.0;
  for (int c = t; c < D; c += 256) { double v = (double)colsum[c]; ss2 += v * v; }
  #pragma unroll
  for (int off = 32; off; off >>= 1) {
    ssq += __shfl_down(ssq, off);
    ss2 += __shfl_down(ss2, off);
  }
  __shared__ double l1[4], l2[4];
  if ((t & 63) == 0) { l1[t >> 6] = ssq; l2[t >> 6] = ss2; }
  __syncthreads();
  if (t == 0) {
    double SSQ = l1[0] + l1[1] + l1[2] + l1[3];
    double SS2 = l2[0] + l2[1] + l2[2] + l2[3];
    double n = (double)NROWS;
    double sum_d2 = 2.0 * n * SSQ - 2.0 * SS2;
    double bw = sum_d2 / (n * n - n) + 1e-8;     // + EPS
    bw = bw * 0.25;                               // / KERNEL_MUL^(KERNEL_NUM//2)
    const double LOG2E = 1.4426950408889634;
    na[0] = (float)(-LOG2E / (bw * 16.0));        // widest kernel (i=4)
  }
}

// ---------------- k3: bf16x3-split MFMA GEMM, dbuf issue-early + swizzled LDS ----------------
// 128x128 tile, BK=32, 4 waves (2x2), wave = 64x64 via 4x4 16x16x32 bf16 frags.
// LDS per buf (shorts): Ahi 0 | Alo 4096 | Bhi 8192 | Blo 12288. Double-buffered (64 KB).
// Swizzle (rule #21): LDS slot (row,k16) holds global chunk (row, k16 ^ ((row>>1)&3));
// write side linear (global_load_lds), source pre-swizzled, read side applies same XOR.
__global__ __launch_bounds__(256) void k_gemm(const unsigned short* __restrict__ hi,
                                              const unsigned short* __restrict__ lo,
                                              const float* __restrict__ sq,
                                              const float* __restrict__ na,
                                              double* __restrict__ part) {
  __shared__ unsigned short lds[2 * 16384];
  __shared__ double red[4];

  int bid0 = blockIdx.x;
  int bid = (bid0 & 7) * (NBLK_GEMM / 8) + (bid0 >> 3);   // XCD swizzle (2080 % 8 == 0)
  int type, bi, bj;
  float wgt = 1.f;
  if (bid < 2 * T_SYM) {
    type = (bid >= T_SYM);
    int idx = bid - type * T_SYM;
    bi = 0;
    while (idx >= TILES - bi) { idx -= TILES - bi; ++bi; }
    bj = bi + idx;
    wgt = (bi == bj) ? 1.f : 2.f;
  } else {
    type = 2;
    int rem = bid - 2 * T_SYM;
    bi = rem >> 5;
    bj = rem & 31;
  }
  int offA = (type == 1) ? NS : 0;
  int offB = (type == 0) ? 0 : NS;

  int t = threadIdx.x;
  int w = t >> 6, l = t & 63;
  int wr = w >> 1, wc = w & 1;
  int fr = l & 15, fk = l >> 4;

  // staging: wave w owns one array: 0=Ahi 1=Alo 2=Bhi 3=Blo (8 KB each per K-step)
  const unsigned short* sarr = (w & 1) ? lo : hi;
  int rbase = ((w < 2) ? (offA + bi * 128) : (offB + bj * 128)) + (l >> 2);
  int gswz = ((l & 3) ^ ((l >> 3) & 3)) * 8;     // pre-swizzled source chunk
  const unsigned short* gbase = sarr + (size_t)rbase * D + gswz;

  int rsw = (fr >> 1) & 3;
  int aoff = (wr * 64 + fr) * 32 + (fk ^ rsw) * 8;          // + m*512
  int boff = 8192 + (wc * 64 + fr) * 32 + (fk ^ rsw) * 8;   // + n*512

  f32x4 acc[4][4];
  f32x4 zero = {0.f, 0.f, 0.f, 0.f};
  #pragma unroll
  for (int m = 0; m < 4; ++m)
    #pragma unroll
    for (int n = 0; n < 4; ++n) acc[m][n] = zero;

  // prologue: stage K-step 0 into buf 0
  #pragma unroll
  for (int c = 0; c < 8; ++c)
    gload_lds16(gbase + (size_t)c * 16 * D, &lds[w * 4096 + c * 512]);
  __syncthreads();

  int cur = 0;
  for (int kt = 0; kt < D / 32; ++kt) {
    int nxt = cur ^ 16384;
    if (kt < D / 32 - 1) {        // issue-early: next tile's loads fly over this tile's MFMAs
      #pragma unroll
      for (int c = 0; c < 8; ++c)
        gload_lds16(gbase + (size_t)c * 16 * D + (kt + 1) * 32, &lds[nxt + w * 4096 + c * 512]);
    }
    bf16x8 ah[4], al[4], bh[4], bl[4];
    #pragma unroll
    for (int m = 0; m < 4; ++m) {
      ah[m] = *(const bf16x8*)&lds[cur + aoff + m * 512];
      al[m] = *(const bf16x8*)&lds[cur + 4096 + aoff + m * 512];
    }
    #pragma unroll
    for (int n = 0; n < 4; ++n) {
      bh[n] = *(const bf16x8*)&lds[cur + boff + n * 512];
      bl[n] = *(const bf16x8*)&lds[cur + 12288 + boff + n * 512];
    }
    __builtin_amdgcn_s_setprio(1);
    #pragma unroll
    for (int m = 0; m < 4; ++m)
      #pragma unroll
      for (int n = 0; n < 4; ++n) {
        acc[m][n] = __builtin_amdgcn_mfma_f32_16x16x32_bf16(ah[m], bh[n], acc[m][n], 0, 0, 0);
        acc[m][n] = __builtin_amdgcn_mfma_f32_16x16x32_bf16(ah[m], bl[n], acc[m][n], 0, 0, 0);
        acc[m][n] = __builtin_amdgcn_mfma_f32_16x16x32_bf16(al[m], bh[n], acc[m][n], 0, 0, 0);
      }
    __builtin_amdgcn_s_setprio(0);
    __syncthreads();              // drains vmcnt(0): publishes kt+1 staging; latency already hidden
    cur = nxt;
  }

  // epilogue: d2 -> u + u^2 + u^4 + u^8 + u^16, u = exp2(d2*na4)
  float na4 = na[0];
  int gi = offA + bi * 128 + wr * 64;
  int gj = offB + bj * 128 + wc * 64;
  float sqa[4][4], sqb[4];
  #pragma unroll
  for (int m = 0; m < 4; ++m)
    #pragma unroll
    for (int j = 0; j < 4; ++j) sqa[m][j] = sq[gi + m * 16 + fk * 4 + j];
  #pragma unroll
  for (int n = 0; n < 4; ++n) sqb[n] = sq[gj + n * 16 + fr];

  double local = 0.0;
  #pragma unroll
  for (int m = 0; m < 4; ++m)
    #pragma unroll
    for (int n = 0; n < 4; ++n) {
      float fs = 0.f;
      #pragma unroll
      for (int j = 0; j < 4; ++j) {
        float d2 = fmaxf(fmaf(-2.f, acc[m][n][j], sqa[m][j] + sqb[n]), 0.f);
        float u = __builtin_amdgcn_exp2f(d2 * na4);
        float u2 = u * u, u4 = u2 * u2, u8 = u4 * u4, u16 = u8 * u8;
        fs += (u + u2) + (u4 + u8) + u16;
      }
      local += (double)fs;
    }
  local *= (double)wgt;
  #pragma unroll
  for (int off = 32; off; off >>= 1) local += __shfl_down(local, off);
  if (l == 0) red[w] = local;
  __syncthreads();
  if (t == 0) part[bid] = red[0] + red[1] + red[2] + red[3];
}

// ---------------- k4: final fp64 reduction + loss ----------------
__global__ __launch_bounds__(256) void k_final(const double* __restrict__ part,
                                               float* __restrict__ out) {
  int t = threadIdx.x;
  double a0 = 0.0, a1 = 0.0, a2 = 0.0;
  for (int i = t; i < T_SYM; i += 256) a0 += part[i];
  for (int i = t; i < T_SYM; i += 256) a1 += part[T_SYM + i];
  for (int i = t; i < TILES * TILES; i += 256) a2 += part[2 * T_SYM + i];
  #pragma unroll
  for (int off = 32; off; off >>= 1) {
    a0 += __shfl_down(a0, off);
    a1 += __shfl_down(a1, off);
    a2 += __shfl_down(a2, off);
  }
  __shared__ double r0[4], r1[4], r2[4];
  if ((t & 63) == 0) { r0[t >> 6] = a0; r1[t >> 6] = a1; r2[t >> 6] = a2; }
  __syncthreads();
  if (t == 0) {
    double A0 = r0[0] + r0[1] + r0[2] + r0[3];
    double A1 = r1[0] + r1[1] + r1[2] + r1[3];
    double A2 = r2[0] + r2[1] + r2[2] + r2[3];
    double ns = (double)NS;
    double loss = (A0 - 5.0 * ns) / (ns * (ns - 1.0))
                + (A1 - 5.0 * ns) / (ns * (ns - 1.0))
                - 2.0 * A2 / (ns * ns);
    out[0] = (float)loss;
  }
}

extern "C" void kernel_launch(void* const* d_in, const int* in_sizes, int n_in,
                              void* d_out, int out_size, void* d_ws, size_t ws_size,
                              hipStream_t stream) {
  (void)in_sizes; (void)n_in; (void)out_size; (void)ws_size;
  const float* src = (const float*)d_in[0];
  const float* tgt = (const float*)d_in[1];
  float* out = (float*)d_out;
  char* ws = (char*)d_ws;

  // ws layout (needs ~17.5 MB):
  double*         part   = (double*)(ws);                   // 2080*8 = 16640
  float*          sq     = (float*)(ws + 0x8000);           // 32 KB
  float*          colsum = (float*)(ws + 0x10000);          // 2 KB
  float*          na     = (float*)(ws + 0x11000);          // 4 B
  unsigned short* hi     = (unsigned short*)(ws + 0x100000);    // 8 MB
  unsigned short* lo     = (unsigned short*)(ws + 0x900000);    // 8 MB

  hipMemsetAsync(colsum, 0, 512 * sizeof(float), stream);
  hipLaunchKernelGGL(k_rownorm, dim3(256), dim3(256), 0, stream, src, tgt, sq, hi, lo, colsum);
  hipLaunchKernelGGL(k_prep, dim3(1), dim3(256), 0, stream, sq, colsum, na);
  hipLaunchKernelGGL(k_gemm, dim3(NBLK_GEMM), dim3(256), 0, stream, hi, lo, sq, na, part);
  hipLaunchKernelGGL(k_final, dim3(1), dim3(256), 0, stream, part, out);
}